// Round 12
// baseline (564.199 us; speedup 1.0000x reference)
//
#include <hip/hip_runtime.h>
#include <hip/hip_bf16.h>

typedef __bf16 bf16;
typedef __bf16 bf16x8 __attribute__((ext_vector_type(8)));
typedef float f32x4 __attribute__((ext_vector_type(4)));
typedef unsigned int u32x2 __attribute__((ext_vector_type(2)));
typedef unsigned int u32x4 __attribute__((ext_vector_type(4)));

#define DEVI static __device__ __forceinline__

static constexpr int Bn = 4, Cc = 192, Hh = 256, Wd = 256;
static constexpr int NHd = 6, HD = 32;
static constexpr int Mtot = Bn * Hh * Wd;          // 262144 pixels
static constexpr float EPSv = 1e-5f;

DEVI f32x4 mfma16(bf16x8 a, bf16x8 b, f32x4 c) {
    return __builtin_amdgcn_mfma_f32_16x16x32_bf16(a, b, c, 0, 0, 0);
}

DEVI f32x4 mfma16f8(long long a, long long b, f32x4 c) {
    return __builtin_amdgcn_mfma_f32_16x16x32_fp8_fp8(a, b, c, 0, 0, 0);
}

DEVI unsigned cvtpk_bf16(float lo, float hi) {
    unsigned r;
    asm("v_cvt_pk_bf16_f32 %0, %1, %2" : "=v"(r) : "v"(lo), "v"(hi));
    return r;
}

template <bool HIGH>
DEVI unsigned cvtpk_fp8(float lo, float hi, unsigned old) {
    return (unsigned)__builtin_amdgcn_cvt_pk_fp8_f32(lo, hi, (int)old, HIGH);
}

// ---------------------------------------------------------------- K0: weights
__global__ __launch_bounds__(256) void k_prep(const float* Wq, const float* Wkv,
                                              const float* Wo, bf16* WT, bf16* WoT) {
    int idx = blockIdx.x * 256 + threadIdx.x;
    if (idx < 576 * 192) {
        int n = idx / 192, k = idx % 192;
        float v = (n < 192) ? Wq[k * 192 + n] : Wkv[k * 384 + (n - 192)];
        WT[idx] = (bf16)v;
    } else if (idx < 576 * 192 + 192 * 192) {
        int j = idx - 576 * 192;
        int n = j / 192, k = j % 192;
        WoT[j] = (bf16)Wo[k * 192 + n];
    }
}

// ---------------------------------------------------------------- K1: fused LN + QKV projection
// r8 structure (nt-outer, W read once). Q,K -> bf16 planes; V -> fp8 plane.
__global__ __launch_bounds__(256) void k_lnqkv(const float* __restrict__ x,
                                               const float* __restrict__ gamma,
                                               const float* __restrict__ beta,
                                               const bf16* __restrict__ WT,
                                               const float* __restrict__ bq,
                                               const float* __restrict__ bkv,
                                               bf16* __restrict__ QK,
                                               unsigned char* __restrict__ V8) {
    constexpr int AS = 200;                       // A-tile stride
    __shared__ __align__(16) bf16 A[64 * AS];
    __shared__ float red[2][4][64];
    __shared__ float sg[Cc], sbv[Cc];

    int tid = threadIdx.x;
    int q = tid >> 6, p = tid & 63;
    int base = blockIdx.x * 64;
    int b = base >> 16;
    int hw = base & 65535;
    int h = hw >> 8, w0 = hw & 255;
    if (tid < Cc) { sg[tid] = gamma[tid]; sbv[tid] = beta[tid]; }

    // pass 1: 48 channels per wave; stats in f32, stash bf16 copy in A
    const float* xb = x + ((size_t)(b * Cc + q * 48) * Hh + h) * Wd + w0 + p;
    float s = 0.f, s2 = 0.f;
#pragma unroll
    for (int i0 = 0; i0 < 48; i0 += 8) {
        bf16x8 o;
#pragma unroll
        for (int j = 0; j < 8; ++j) {
            float v = xb[(size_t)(i0 + j) * Hh * Wd];
            s += v; s2 += v * v; o[j] = (bf16)v;
        }
        *(bf16x8*)&A[p * AS + q * 48 + i0] = o;
    }
    red[0][q][p] = s; red[1][q][p] = s2;
    __syncthreads();
    float mu = (red[0][0][p] + red[0][1][p] + red[0][2][p] + red[0][3][p]) * (1.f / 192.f);
    float m2 = (red[1][0][p] + red[1][1][p] + red[1][2][p] + red[1][3][p]) * (1.f / 192.f);
    float rs = rsqrtf(m2 - mu * mu + EPSv);
    // pass 2: normalize in place
#pragma unroll
    for (int i0 = 0; i0 < 48; i0 += 8) {
        bf16x8 v8 = *(bf16x8*)&A[p * AS + q * 48 + i0];
        bf16x8 o;
#pragma unroll
        for (int j = 0; j < 8; ++j) {
            int c = q * 48 + i0 + j;
            o[j] = (bf16)(((float)v8[j] - mu) * rs * sg[c] + sbv[c]);
        }
        *(bf16x8*)&A[p * AS + q * 48 + i0] = o;
    }
    __syncthreads();

    // GEMM: 4 waves x 144 cols; nt streamed OUTER (W read once), mt inner.
    int lane = tid & 63, l15 = lane & 15, g = lane >> 4;
    const bf16* Wbase = WT + (size_t)(q * 144 + l15) * Cc + g * 8;
#pragma unroll 1
    for (int nt = 0; nt < 9; ++nt) {
        f32x4 acc[4] = {};
        const bf16* wp = Wbase + (size_t)nt * 16 * Cc;
#pragma unroll
        for (int kk = 0; kk < 6; ++kk) {
            bf16x8 wb = *(const bf16x8*)(wp + kk * 32);
#pragma unroll
            for (int mt = 0; mt < 4; ++mt) {
                bf16x8 a = *(bf16x8*)&A[(mt * 16 + l15) * AS + kk * 32 + g * 8];
                acc[mt] = mfma16(wb, a, acc[mt]);   // D[n][pix]
            }
        }
        int n0 = q * 144 + nt * 16 + g * 4;         // 4-group never crosses plane
        const float* bsrc = (n0 < 192) ? (bq + n0) : (bkv + n0 - 192);
        f32x4 b4 = *(const f32x4*)bsrc;
        if (n0 < 384) {                              // Q or K bf16 plane
            bf16* outp = QK + (size_t)(n0 >> 5) * Mtot * HD + (n0 & 31);
#pragma unroll
            for (int mt = 0; mt < 4; ++mt) {
                u32x2 pk;
                pk[0] = cvtpk_bf16(acc[mt][0] + b4[0], acc[mt][1] + b4[1]);
                pk[1] = cvtpk_bf16(acc[mt][2] + b4[2], acc[mt][3] + b4[3]);
                *(u32x2*)(outp + (size_t)(base + mt * 16 + l15) * HD) = pk;
            }
        } else {                                     // V fp8 plane [pix][32]
            int vh = (n0 - 384) >> 5;
            unsigned char* outp = V8 + (size_t)vh * Mtot * HD + ((n0 - 384) & 31);
#pragma unroll
            for (int mt = 0; mt < 4; ++mt) {
                unsigned pk = 0;
                pk = cvtpk_fp8<false>(acc[mt][0] + b4[0], acc[mt][1] + b4[1], pk);
                pk = cvtpk_fp8<true>(acc[mt][2] + b4[2], acc[mt][3] + b4[3], pk);
                *(unsigned*)(outp + (size_t)(base + mt * 16 + l15) * HD) = pk;
            }
        }
    }
}

// ---------------------------------------------------------------- K1b: V transpose
// fp8 V [head][pix][32] -> Vt [head][d][pix]. Block = 256 pixels of one head.
__global__ __launch_bounds__(256) void k_vt(const unsigned char* __restrict__ V8,
                                            unsigned char* __restrict__ Vt8) {
    int bid = blockIdx.x;
    int head = bid >> 10;
    int pbase = (bid & 1023) << 8;
    const unsigned char* src = V8 + ((size_t)head * Mtot + pbase) * HD;
    unsigned char* dst = Vt8 + (size_t)head * HD * Mtot + pbase;
    __shared__ __align__(16) unsigned char T[32 * 264];
    int t = threadIdx.x;
    u32x4 a0 = *(const u32x4*)(src + t * 32);
    u32x4 a1 = *(const u32x4*)(src + t * 32 + 16);
#pragma unroll
    for (int w = 0; w < 4; ++w) {
        unsigned x0 = a0[w], x1 = a1[w];
#pragma unroll
        for (int by = 0; by < 4; ++by) {
            T[(w * 4 + by) * 264 + t] = (unsigned char)(x0 >> (8 * by));
            T[(16 + w * 4 + by) * 264 + t] = (unsigned char)(x1 >> (8 * by));
        }
    }
    __syncthreads();
    int d = t >> 3, ck = (t & 7) * 32;
    u32x4 o0 = *(const u32x4*)&T[d * 264 + ck];
    u32x4 o1 = *(const u32x4*)&T[d * 264 + ck + 16];
    *(u32x4*)(dst + (size_t)d * Mtot + ck) = o0;
    *(u32x4*)(dst + (size_t)d * Mtot + ck + 16) = o1;
}

// ---------------------------------------------------------------- K2: attention
// fp8 PV; V staged from pre-transposed global plane (2x16B loads/thread);
// softmax without row-max (scores tiny; shift-invariant).
__global__ __launch_bounds__(256) void k_attn(const bf16* __restrict__ QK,
                                              const unsigned char* __restrict__ Vt8,
                                              const float* __restrict__ bkv,
                                              bf16* __restrict__ O) {
    constexpr int PS = 272;                        // P row stride BYTES
    constexpr int VS = 272;                        // VT row stride BYTES (16B aligned)
    int bid = blockIdx.x;
    bid = (bid & 7) * 3072 + (bid >> 3);          // chunked XCD swizzle (24576 = 8*3072)
    int head = bid >> 12;                          // /4096
    int win = bid & 4095;
    int b = win >> 10, wloc = win & 1023;
    int h0 = ((wloc >> 5) << 3), w0 = ((wloc & 31) << 3);
    bool interior = (h0 != 0) && (h0 != Hh - 8) && (w0 != 0) && (w0 != Wd - 8);

    int tid = threadIdx.x, wave = tid >> 6, lane = tid & 63;
    int l15 = lane & 15, g = lane >> 4;

    const bf16* Qh = QK + (size_t)head * Mtot * HD;
    const bf16* Kh = QK + (size_t)(6 + head) * Mtot * HD;
    const unsigned char* Vth = Vt8 + (size_t)head * HD * Mtot;
    bf16* Oh = O + (size_t)head * Mtot * HD;
    long long p00 = (long long)(b * Hh + h0 - 4) * Wd + (w0 - 4);

    __shared__ __align__(16) unsigned char VT8[32 * VS];  // fp8 V^T [d][kv]
    __shared__ __align__(16) unsigned char P8[64 * PS];   // fp8 probs [qrow][kv]

    // ---- stage V^T from pre-transposed plane: thread = (d, row-pair)
    {
        int d = tid >> 3;
        int rowp = (tid & 7) * 2;
        float vbd = bkv[Cc + head * HD + d];
        unsigned bias4 = (cvtpk_fp8<false>(vbd, vbd, 0u) & 0xFFu) * 0x01010101u;
        unsigned keep0 = (w0 == 0) ? 0u : 0xFFFFFFFFu;
        unsigned keep3 = (w0 == Wd - 8) ? 0u : 0xFFFFFFFFu;
        const unsigned char* vsrc = Vth + (size_t)d * Mtot;
#pragma unroll
        for (int rr = 0; rr < 2; ++rr) {
            int row = rowp + rr;
            int ph = h0 - 4 + row;
            bool rowok = ((unsigned)ph < (unsigned)Hh);
            long long pix = (long long)(b * Hh + ph) * Wd + (w0 - 4);
            pix = rowok ? pix : 0;
            u32x4 v = *(const u32x4*)(vsrc + pix);
            if (rowok) {
                v[0] = (v[0] & keep0) | (bias4 & ~keep0);
                v[3] = (v[3] & keep3) | (bias4 & ~keep3);
            } else {
                v[0] = bias4; v[1] = bias4; v[2] = bias4; v[3] = bias4;
            }
            *(u32x4*)&VT8[d * VS + row * 16] = v;
        }
    }

    // ---- Q fragment (B-operand): lane l15 holds Q row wave*16+l15
    int qr = wave * 16 + l15;
    size_t qpix = (size_t)(b * Hh + h0 + (qr >> 3)) * Wd + w0 + (qr & 7);
    bf16x8 aq = *(const bf16x8*)(Qh + qpix * HD + g * 8);
    __syncthreads();

    // ---- S^T = K @ Q^T : 16 kv-tiles; lane -> (kv = t*16+g*4+r, q = l15)
    f32x4 s[16];
    const f32x4 z = {0.f, 0.f, 0.f, 0.f};
    const bf16* kp = Kh + (p00 + l15) * HD + g * 8;
    if (interior) {
#pragma unroll
        for (int t = 0; t < 16; ++t) {
            bf16x8 kf = *(const bf16x8*)(kp + (size_t)t * Wd * HD);
            s[t] = mfma16(kf, aq, z);
        }
    } else {
        bf16x8 kb;
#pragma unroll
        for (int j = 0; j < 8; ++j) kb[j] = (bf16)bkv[head * HD + g * 8 + j];
        bool colok = ((unsigned)(w0 - 4 + l15) < (unsigned)Wd);
#pragma unroll
        for (int t = 0; t < 16; ++t) {
            int ph = h0 - 4 + t;                  // wave-uniform
            bf16x8 kf;
            if ((unsigned)ph < (unsigned)Hh) {
                kf = *(const bf16x8*)(kp + (size_t)t * Wd * HD);
                kf = colok ? kf : kb;
            } else {
                kf = kb;
            }
            s[t] = mfma16(kf, aq, z);
        }
    }

    // ---- softmax WITHOUT row-max (scores tiny; softmax is shift-invariant)
    const float sc = 0.17677669529663689f * 1.4426950408889634f; // scale * log2(e)
    float sr0 = 0.f, sr1 = 0.f, sr2 = 0.f, sr3 = 0.f;
    int prow = wave * 16 + l15;
#pragma unroll
    for (int t = 0; t < 16; ++t) {
        float p0 = __builtin_amdgcn_exp2f(s[t][0] * sc);
        float p1 = __builtin_amdgcn_exp2f(s[t][1] * sc);
        float p2 = __builtin_amdgcn_exp2f(s[t][2] * sc);
        float p3 = __builtin_amdgcn_exp2f(s[t][3] * sc);
        sr0 += p0; sr1 += p1; sr2 += p2; sr3 += p3;
        unsigned pk = 0;
        pk = cvtpk_fp8<false>(p0, p1, pk);
        pk = cvtpk_fp8<true>(p2, p3, pk);
        *(unsigned*)&P8[prow * PS + t * 16 + g * 4] = pk;
    }
    float sum = (sr0 + sr1) + (sr2 + sr3);
    sum += __shfl_xor(sum, 16);
    sum += __shfl_xor(sum, 32);
    float inv = __builtin_amdgcn_rcpf(sum);
    __builtin_amdgcn_wave_barrier();   // P rows are wave-private; ordering only

    // ---- O = P @ V in fp8 (normalize at epilogue)
    f32x4 o[2] = {};
#pragma unroll
    for (int kk = 0; kk < 8; ++kk) {
        long long ap = *(const long long*)&P8[prow * PS + kk * 32 + g * 8];
#pragma unroll
        for (int nt = 0; nt < 2; ++nt) {
            long long bv = *(const long long*)&VT8[(nt * 16 + l15) * VS + kk * 32 + g * 8];
            o[nt] = mfma16f8(ap, bv, o[nt]);
        }
    }
    // inv for epilogue rows g*4+r lives in lanes with l15 == g*4+r (same g ok)
    float invr[4];
#pragma unroll
    for (int r = 0; r < 4; ++r)
        invr[r] = __shfl(inv, (lane & 48) | (g * 4 + r));
#pragma unroll
    for (int nt = 0; nt < 2; ++nt)
#pragma unroll
        for (int r = 0; r < 4; ++r) {
            int row = wave * 16 + g * 4 + r;
            size_t pix = (size_t)(b * Hh + h0 + (row >> 3)) * Wd + w0 + (row & 7);
            Oh[pix * HD + nt * 16 + l15] = (bf16)(o[nt][r] * invr[r]);
        }
}

// ---------------------------------------------------------------- K3: O-proj + residual (BHWC->BCHW)
__global__ __launch_bounds__(256) void k_out(const bf16* __restrict__ AO,
                                             const bf16* __restrict__ WoT,
                                             const float* __restrict__ bo,
                                             const float* __restrict__ x,
                                             float* __restrict__ out) {
    int row0 = blockIdx.x * 64;
    int tid = threadIdx.x, wave = tid >> 6, lane = tid & 63;
    int l15 = lane & 15, g = lane >> 4;
    int nb = wave * 48;
    f32x4 acc[4][3] = {};
    const bf16* Arow[4];
#pragma unroll
    for (int mt = 0; mt < 4; ++mt) Arow[mt] = AO + (size_t)(row0 + mt * 16 + l15) * HD + g * 8;
    const bf16* Wrow[3];
#pragma unroll
    for (int nt = 0; nt < 3; ++nt) Wrow[nt] = WoT + (size_t)(nb + nt * 16 + l15) * Cc + g * 8;
#pragma unroll
    for (int kk = 0; kk < 6; ++kk) {
        bf16x8 a[4];
#pragma unroll
        for (int mt = 0; mt < 4; ++mt)
            a[mt] = *(const bf16x8*)(Arow[mt] + (size_t)kk * Mtot * HD);
#pragma unroll
        for (int nt = 0; nt < 3; ++nt) {
            bf16x8 bb = *(const bf16x8*)(Wrow[nt] + kk * 32);
#pragma unroll
            for (int mt = 0; mt < 4; ++mt) acc[mt][nt] = mfma16(a[mt], bb, acc[mt][nt]);
        }
    }
    __shared__ float st[192 * 65];
#pragma unroll
    for (int nt = 0; nt < 3; ++nt) {
        float bval = bo[nb + nt * 16 + l15];
#pragma unroll
        for (int mt = 0; mt < 4; ++mt)
#pragma unroll
            for (int r = 0; r < 4; ++r) {
                int ccol = nb + nt * 16 + l15;
                int px = mt * 16 + g * 4 + r;
                st[ccol * 65 + px] = acc[mt][nt][r] + bval;
            }
    }
    __syncthreads();
    int bb2 = row0 / (Hh * Wd);
    int rem = row0 % (Hh * Wd);
    int h = rem / Wd, wstart = rem % Wd;
    for (int idx = tid; idx < 192 * 64; idx += 256) {
        int cc = idx >> 6, px = idx & 63;
        size_t ga = ((size_t)(bb2 * Cc + cc) * Hh + h) * Wd + wstart + px;
        out[ga] = st[cc * 65 + px] + x[ga];
    }
}

// ---------------------------------------------------------------- launch
extern "C" void kernel_launch(void* const* d_in, const int* in_sizes, int n_in,
                              void* d_out, int out_size, void* d_ws, size_t ws_size,
                              hipStream_t stream) {
    const float* x     = (const float*)d_in[0];
    const float* gamma = (const float*)d_in[1];
    const float* beta  = (const float*)d_in[2];
    const float* Wq    = (const float*)d_in[3];
    const float* bq    = (const float*)d_in[4];
    const float* Wkv   = (const float*)d_in[5];
    const float* bkv   = (const float*)d_in[6];
    const float* Wo    = (const float*)d_in[7];
    const float* bo    = (const float*)d_in[8];
    float* out = (float*)d_out;

    char* ws = (char*)d_ws;
    constexpr size_t PLANE = (size_t)Mtot * HD * 2;        // 16777216 B (bf16 plane)
    constexpr size_t QKSZ  = 12 * PLANE;                    // Q(6) + K(6) = 201326592
    constexpr size_t V8SZ  = (size_t)NHd * Mtot * HD;       // 50331648 B (fp8)
    constexpr size_t VTSZ  = V8SZ + 65536;                  // + OOB-read pad
    bf16*          QK  = (bf16*)(ws);
    unsigned char* V8  = (unsigned char*)(ws + QKSZ);
    unsigned char* Vt8 = (unsigned char*)(ws + QKSZ + V8SZ);
    bf16*          AO  = (bf16*)(ws + QKSZ + V8SZ + VTSZ);  // 6 bf16 planes
    bf16*          WT  = (bf16*)(ws + QKSZ + V8SZ + VTSZ + 6 * PLANE);
    bf16*          WoT = (bf16*)(ws + QKSZ + V8SZ + VTSZ + 6 * PLANE + 221184);

    k_prep<<<576, 256, 0, stream>>>(Wq, Wkv, Wo, WT, WoT);
    k_lnqkv<<<Mtot / 64, 256, 0, stream>>>(x, gamma, beta, WT, bq, bkv, QK, V8);
    k_vt<<<NHd * 1024, 256, 0, stream>>>(V8, Vt8);
    k_attn<<<4096 * NHd, 256, 0, stream>>>(QK, Vt8, bkv, AO);
    k_out<<<Mtot / 64, 256, 0, stream>>>(AO, WoT, bo, x, out);
}

// Round 13
// 513.996 us; speedup vs baseline: 1.0977x; 1.0977x over previous
//
#include <hip/hip_runtime.h>
#include <hip/hip_bf16.h>

typedef __bf16 bf16;
typedef __bf16 bf16x8 __attribute__((ext_vector_type(8)));
typedef float f32x4 __attribute__((ext_vector_type(4)));
typedef unsigned int u32x2 __attribute__((ext_vector_type(2)));
typedef unsigned int u32x4 __attribute__((ext_vector_type(4)));

#define DEVI static __device__ __forceinline__

static constexpr int Bn = 4, Cc = 192, Hh = 256, Wd = 256;
static constexpr int NHd = 6, HD = 32;
static constexpr int Mtot = Bn * Hh * Wd;          // 262144 pixels
static constexpr float EPSv = 1e-5f;

DEVI f32x4 mfma16(bf16x8 a, bf16x8 b, f32x4 c) {
    return __builtin_amdgcn_mfma_f32_16x16x32_bf16(a, b, c, 0, 0, 0);
}

DEVI f32x4 mfma16f8(long long a, long long b, f32x4 c) {
    return __builtin_amdgcn_mfma_f32_16x16x32_fp8_fp8(a, b, c, 0, 0, 0);
}

DEVI unsigned cvtpk_bf16(float lo, float hi) {
    unsigned r;
    asm("v_cvt_pk_bf16_f32 %0, %1, %2" : "=v"(r) : "v"(lo), "v"(hi));
    return r;
}

template <bool HIGH>
DEVI unsigned cvtpk_fp8(float lo, float hi, unsigned old) {
    return (unsigned)__builtin_amdgcn_cvt_pk_fp8_f32(lo, hi, (int)old, HIGH);
}

// ---------------------------------------------------------------- K0: weights
__global__ __launch_bounds__(256) void k_prep(const float* Wq, const float* Wkv,
                                              const float* Wo, bf16* WT, bf16* WoT) {
    int idx = blockIdx.x * 256 + threadIdx.x;
    if (idx < 576 * 192) {
        int n = idx / 192, k = idx % 192;
        float v = (n < 192) ? Wq[k * 192 + n] : Wkv[k * 384 + (n - 192)];
        WT[idx] = (bf16)v;
    } else if (idx < 576 * 192 + 192 * 192) {
        int j = idx - 576 * 192;
        int n = j / 192, k = j % 192;
        WoT[j] = (bf16)Wo[k * 192 + n];
    }
}

// ---------------------------------------------------------------- K1: fused LN + QKV projection
// r8 structure (nt-outer, W read once). Q,K -> bf16 planes; V -> fp8 plane.
__global__ __launch_bounds__(256) void k_lnqkv(const float* __restrict__ x,
                                               const float* __restrict__ gamma,
                                               const float* __restrict__ beta,
                                               const bf16* __restrict__ WT,
                                               const float* __restrict__ bq,
                                               const float* __restrict__ bkv,
                                               bf16* __restrict__ QK,
                                               unsigned char* __restrict__ V8) {
    constexpr int AS = 200;                       // A-tile stride
    __shared__ __align__(16) bf16 A[64 * AS];
    __shared__ float red[2][4][64];
    __shared__ float sg[Cc], sbv[Cc];

    int tid = threadIdx.x;
    int q = tid >> 6, p = tid & 63;
    int base = blockIdx.x * 64;
    int b = base >> 16;
    int hw = base & 65535;
    int h = hw >> 8, w0 = hw & 255;
    if (tid < Cc) { sg[tid] = gamma[tid]; sbv[tid] = beta[tid]; }

    // pass 1: 48 channels per wave; stats in f32, stash bf16 copy in A
    const float* xb = x + ((size_t)(b * Cc + q * 48) * Hh + h) * Wd + w0 + p;
    float s = 0.f, s2 = 0.f;
#pragma unroll
    for (int i0 = 0; i0 < 48; i0 += 8) {
        bf16x8 o;
#pragma unroll
        for (int j = 0; j < 8; ++j) {
            float v = xb[(size_t)(i0 + j) * Hh * Wd];
            s += v; s2 += v * v; o[j] = (bf16)v;
        }
        *(bf16x8*)&A[p * AS + q * 48 + i0] = o;
    }
    red[0][q][p] = s; red[1][q][p] = s2;
    __syncthreads();
    float mu = (red[0][0][p] + red[0][1][p] + red[0][2][p] + red[0][3][p]) * (1.f / 192.f);
    float m2 = (red[1][0][p] + red[1][1][p] + red[1][2][p] + red[1][3][p]) * (1.f / 192.f);
    float rs = rsqrtf(m2 - mu * mu + EPSv);
    // pass 2: normalize in place
#pragma unroll
    for (int i0 = 0; i0 < 48; i0 += 8) {
        bf16x8 v8 = *(bf16x8*)&A[p * AS + q * 48 + i0];
        bf16x8 o;
#pragma unroll
        for (int j = 0; j < 8; ++j) {
            int c = q * 48 + i0 + j;
            o[j] = (bf16)(((float)v8[j] - mu) * rs * sg[c] + sbv[c]);
        }
        *(bf16x8*)&A[p * AS + q * 48 + i0] = o;
    }
    __syncthreads();

    // GEMM: 4 waves x 144 cols; nt streamed OUTER (W read once), mt inner.
    int lane = tid & 63, l15 = lane & 15, g = lane >> 4;
    const bf16* Wbase = WT + (size_t)(q * 144 + l15) * Cc + g * 8;
#pragma unroll 1
    for (int nt = 0; nt < 9; ++nt) {
        f32x4 acc[4] = {};
        const bf16* wp = Wbase + (size_t)nt * 16 * Cc;
#pragma unroll
        for (int kk = 0; kk < 6; ++kk) {
            bf16x8 wb = *(const bf16x8*)(wp + kk * 32);
#pragma unroll
            for (int mt = 0; mt < 4; ++mt) {
                bf16x8 a = *(bf16x8*)&A[(mt * 16 + l15) * AS + kk * 32 + g * 8];
                acc[mt] = mfma16(wb, a, acc[mt]);   // D[n][pix]
            }
        }
        int n0 = q * 144 + nt * 16 + g * 4;         // 4-group never crosses plane
        const float* bsrc = (n0 < 192) ? (bq + n0) : (bkv + n0 - 192);
        f32x4 b4 = *(const f32x4*)bsrc;
        if (n0 < 384) {                              // Q or K bf16 plane
            bf16* outp = QK + (size_t)(n0 >> 5) * Mtot * HD + (n0 & 31);
#pragma unroll
            for (int mt = 0; mt < 4; ++mt) {
                u32x2 pk;
                pk[0] = cvtpk_bf16(acc[mt][0] + b4[0], acc[mt][1] + b4[1]);
                pk[1] = cvtpk_bf16(acc[mt][2] + b4[2], acc[mt][3] + b4[3]);
                *(u32x2*)(outp + (size_t)(base + mt * 16 + l15) * HD) = pk;
            }
        } else {                                     // V fp8 plane [pix][32]
            int vh = (n0 - 384) >> 5;
            unsigned char* outp = V8 + (size_t)vh * Mtot * HD + ((n0 - 384) & 31);
#pragma unroll
            for (int mt = 0; mt < 4; ++mt) {
                unsigned pk = 0;
                pk = cvtpk_fp8<false>(acc[mt][0] + b4[0], acc[mt][1] + b4[1], pk);
                pk = cvtpk_fp8<true>(acc[mt][2] + b4[2], acc[mt][3] + b4[3], pk);
                *(unsigned*)(outp + (size_t)(base + mt * 16 + l15) * HD) = pk;
            }
        }
    }
}

// ---------------------------------------------------------------- K2: attention
// fp8 PV. P kept entirely IN REGISTERS; PV A-fragments assembled by lane
// shuffles (producer/consumer lanes differ only in g bits). LDS = V^T only
// (8.4KB). Softmax without row-max (scores tiny; shift-invariant).
__global__ __launch_bounds__(256) void k_attn(const bf16* __restrict__ QK,
                                              const unsigned char* __restrict__ V8,
                                              const float* __restrict__ bkv,
                                              bf16* __restrict__ O) {
    constexpr int VS = 264;                        // VT row stride BYTES
    int bid = blockIdx.x;
    bid = (bid & 7) * 3072 + (bid >> 3);          // chunked XCD swizzle (24576 = 8*3072)
    int head = bid >> 12;                          // /4096
    int win = bid & 4095;
    int b = win >> 10, wloc = win & 1023;
    int h0 = ((wloc >> 5) << 3), w0 = ((wloc & 31) << 3);
    bool interior = (h0 != 0) && (h0 != Hh - 8) && (w0 != 0) && (w0 != Wd - 8);

    int tid = threadIdx.x, wave = tid >> 6, lane = tid & 63;
    int l15 = lane & 15, g = lane >> 4;

    const bf16* Qh = QK + (size_t)head * Mtot * HD;
    const bf16* Kh = QK + (size_t)(6 + head) * Mtot * HD;
    const unsigned char* Vh = V8 + (size_t)head * Mtot * HD;
    bf16* Oh = O + (size_t)head * Mtot * HD;
    long long p00 = (long long)(b * Hh + h0 - 4) * Wd + (w0 - 4);

    __shared__ __align__(16) unsigned char VT8[32 * VS];  // fp8 V^T [d][kv]

    // ---- stage V^T (one kv row per thread), fp8 (r11-proven byte writes)
    {
        int r = tid;
        unsigned wv[8];
        if (interior) {
            const unsigned char* vr = Vh + (p00 + (r >> 4) * Wd + (r & 15)) * HD;
            u32x4 a0 = *(const u32x4*)(vr);
            u32x4 a1 = *(const u32x4*)(vr + 16);
#pragma unroll
            for (int w = 0; w < 4; ++w) { wv[w] = a0[w]; wv[w + 4] = a1[w]; }
        } else {
            int ph = h0 - 4 + (r >> 4), pw = w0 - 4 + (r & 15);
            bool ok = ((unsigned)ph < (unsigned)Hh) && ((unsigned)pw < (unsigned)Wd);
            long long pix = ok ? ((long long)(b * Hh + ph) * Wd + pw) : 0;
            const unsigned char* vr = Vh + pix * HD;
            u32x4 a0 = *(const u32x4*)(vr);
            u32x4 a1 = *(const u32x4*)(vr + 16);
            const float* vb = bkv + Cc + head * HD;
#pragma unroll
            for (int w = 0; w < 8; ++w) {
                unsigned bw = 0;
                bw = cvtpk_fp8<false>(vb[4 * w], vb[4 * w + 1], bw);
                bw = cvtpk_fp8<true>(vb[4 * w + 2], vb[4 * w + 3], bw);
                unsigned lw = (w < 4) ? a0[w] : a1[w - 4];
                wv[w] = ok ? lw : bw;
            }
        }
#pragma unroll
        for (int w = 0; w < 8; ++w) {
            unsigned word = wv[w];
            VT8[(4 * w + 0) * VS + r] = (unsigned char)(word);
            VT8[(4 * w + 1) * VS + r] = (unsigned char)(word >> 8);
            VT8[(4 * w + 2) * VS + r] = (unsigned char)(word >> 16);
            VT8[(4 * w + 3) * VS + r] = (unsigned char)(word >> 24);
        }
    }

    // ---- Q fragment (B-operand): lane l15 holds Q row wave*16+l15
    int qr = wave * 16 + l15;
    size_t qpix = (size_t)(b * Hh + h0 + (qr >> 3)) * Wd + w0 + (qr & 7);
    bf16x8 aq = *(const bf16x8*)(Qh + qpix * HD + g * 8);
    __syncthreads();

    // ---- S^T = K @ Q^T : 16 kv-tiles; lane -> (kv = t*16+g*4+r, q = l15)
    f32x4 s[16];
    const f32x4 z = {0.f, 0.f, 0.f, 0.f};
    const bf16* kp = Kh + (p00 + l15) * HD + g * 8;
    if (interior) {
#pragma unroll
        for (int t = 0; t < 16; ++t) {
            bf16x8 kf = *(const bf16x8*)(kp + (size_t)t * Wd * HD);
            s[t] = mfma16(kf, aq, z);
        }
    } else {
        bf16x8 kb;
#pragma unroll
        for (int j = 0; j < 8; ++j) kb[j] = (bf16)bkv[head * HD + g * 8 + j];
        bool colok = ((unsigned)(w0 - 4 + l15) < (unsigned)Wd);
#pragma unroll
        for (int t = 0; t < 16; ++t) {
            int ph = h0 - 4 + t;                  // wave-uniform
            bf16x8 kf;
            if ((unsigned)ph < (unsigned)Hh) {
                kf = *(const bf16x8*)(kp + (size_t)t * Wd * HD);
                kf = colok ? kf : kb;
            } else {
                kf = kb;
            }
            s[t] = mfma16(kf, aq, z);
        }
    }

    // ---- softmax WITHOUT row-max; P packed fp8 in registers pk[16]
    const float sc = 0.17677669529663689f * 1.4426950408889634f; // scale * log2(e)
    float sr0 = 0.f, sr1 = 0.f, sr2 = 0.f, sr3 = 0.f;
    unsigned pk[16];
#pragma unroll
    for (int t = 0; t < 16; ++t) {
        float p0 = __builtin_amdgcn_exp2f(s[t][0] * sc);
        float p1 = __builtin_amdgcn_exp2f(s[t][1] * sc);
        float p2 = __builtin_amdgcn_exp2f(s[t][2] * sc);
        float p3 = __builtin_amdgcn_exp2f(s[t][3] * sc);
        sr0 += p0; sr1 += p1; sr2 += p2; sr3 += p3;
        unsigned w = 0;
        w = cvtpk_fp8<false>(p0, p1, w);
        w = cvtpk_fp8<true>(p2, p3, w);
        pk[t] = w;
    }
    float sum = (sr0 + sr1) + (sr2 + sr3);
    sum += __shfl_xor(sum, 16);
    sum += __shfl_xor(sum, 32);
    float inv = __builtin_amdgcn_rcpf(sum);

    // ---- O = P @ V in fp8; A-fragments gathered by lane shuffle:
    // lane(l15,g) needs P(q=l15, kv=kk*32+g*8..+7) = u32 pair from lanes
    // (l15 | 2(g&1)<<4) and (l15 | (2(g&1)+1)<<4), register 2kk + (g>>1).
    f32x4 o[2] = {};
    int srcA = l15 | ((2 * (g & 1)) << 4);
    int srcB = srcA + 16;
    bool ghi = (g >> 1) != 0;
#pragma unroll
    for (int kk = 0; kk < 8; ++kk) {
        unsigned sa = __shfl(pk[2 * kk], srcA);
        unsigned sb = __shfl(pk[2 * kk + 1], srcA);
        unsigned scc = __shfl(pk[2 * kk], srcB);
        unsigned sd = __shfl(pk[2 * kk + 1], srcB);
        unsigned lo = ghi ? sb : sa;
        unsigned hi = ghi ? sd : scc;
        long long ap = (long long)(((unsigned long long)hi << 32) | lo);
#pragma unroll
        for (int nt = 0; nt < 2; ++nt) {
            long long bv = *(const long long*)&VT8[(nt * 16 + l15) * VS + kk * 32 + g * 8];
            o[nt] = mfma16f8(ap, bv, o[nt]);
        }
    }
    // inv for epilogue rows g*4+r lives in lanes with l15 == g*4+r (same g ok)
    float invr[4];
#pragma unroll
    for (int r = 0; r < 4; ++r)
        invr[r] = __shfl(inv, (lane & 48) | (g * 4 + r));
#pragma unroll
    for (int nt = 0; nt < 2; ++nt)
#pragma unroll
        for (int r = 0; r < 4; ++r) {
            int row = wave * 16 + g * 4 + r;
            size_t pix = (size_t)(b * Hh + h0 + (row >> 3)) * Wd + w0 + (row & 7);
            Oh[pix * HD + nt * 16 + l15] = (bf16)(o[nt][r] * invr[r]);
        }
}

// ---------------------------------------------------------------- K3: O-proj + residual (BHWC->BCHW)
__global__ __launch_bounds__(256) void k_out(const bf16* __restrict__ AO,
                                             const bf16* __restrict__ WoT,
                                             const float* __restrict__ bo,
                                             const float* __restrict__ x,
                                             float* __restrict__ out) {
    int row0 = blockIdx.x * 64;
    int tid = threadIdx.x, wave = tid >> 6, lane = tid & 63;
    int l15 = lane & 15, g = lane >> 4;
    int nb = wave * 48;
    f32x4 acc[4][3] = {};
    const bf16* Arow[4];
#pragma unroll
    for (int mt = 0; mt < 4; ++mt) Arow[mt] = AO + (size_t)(row0 + mt * 16 + l15) * HD + g * 8;
    const bf16* Wrow[3];
#pragma unroll
    for (int nt = 0; nt < 3; ++nt) Wrow[nt] = WoT + (size_t)(nb + nt * 16 + l15) * Cc + g * 8;
#pragma unroll
    for (int kk = 0; kk < 6; ++kk) {
        bf16x8 a[4];
#pragma unroll
        for (int mt = 0; mt < 4; ++mt)
            a[mt] = *(const bf16x8*)(Arow[mt] + (size_t)kk * Mtot * HD);
#pragma unroll
        for (int nt = 0; nt < 3; ++nt) {
            bf16x8 bb = *(const bf16x8*)(Wrow[nt] + kk * 32);
#pragma unroll
            for (int mt = 0; mt < 4; ++mt) acc[mt][nt] = mfma16(a[mt], bb, acc[mt][nt]);
        }
    }
    __shared__ float st[192 * 65];
#pragma unroll
    for (int nt = 0; nt < 3; ++nt) {
        float bval = bo[nb + nt * 16 + l15];
#pragma unroll
        for (int mt = 0; mt < 4; ++mt)
#pragma unroll
            for (int r = 0; r < 4; ++r) {
                int ccol = nb + nt * 16 + l15;
                int px = mt * 16 + g * 4 + r;
                st[ccol * 65 + px] = acc[mt][nt][r] + bval;
            }
    }
    __syncthreads();
    int bb2 = row0 / (Hh * Wd);
    int rem = row0 % (Hh * Wd);
    int h = rem / Wd, wstart = rem % Wd;
    for (int idx = tid; idx < 192 * 64; idx += 256) {
        int cc = idx >> 6, px = idx & 63;
        size_t ga = ((size_t)(bb2 * Cc + cc) * Hh + h) * Wd + wstart + px;
        out[ga] = st[cc * 65 + px] + x[ga];
    }
}

// ---------------------------------------------------------------- launch
extern "C" void kernel_launch(void* const* d_in, const int* in_sizes, int n_in,
                              void* d_out, int out_size, void* d_ws, size_t ws_size,
                              hipStream_t stream) {
    const float* x     = (const float*)d_in[0];
    const float* gamma = (const float*)d_in[1];
    const float* beta  = (const float*)d_in[2];
    const float* Wq    = (const float*)d_in[3];
    const float* bq    = (const float*)d_in[4];
    const float* Wkv   = (const float*)d_in[5];
    const float* bkv   = (const float*)d_in[6];
    const float* Wo    = (const float*)d_in[7];
    const float* bo    = (const float*)d_in[8];
    float* out = (float*)d_out;

    char* ws = (char*)d_ws;
    constexpr size_t PLANE = (size_t)Mtot * HD * 2;        // 16777216 B (bf16 plane)
    constexpr size_t QKSZ  = 12 * PLANE;                    // Q(6) + K(6)
    constexpr size_t V8SZ  = (size_t)NHd * Mtot * HD;       // 50331648 B (fp8)
    bf16*          QK  = (bf16*)(ws);
    unsigned char* V8  = (unsigned char*)(ws + QKSZ);
    bf16*          AO  = (bf16*)(ws + QKSZ + V8SZ);         // 6 bf16 planes
    bf16*          WT  = (bf16*)(ws + QKSZ + V8SZ + 6 * PLANE);
    bf16*          WoT = (bf16*)(ws + QKSZ + V8SZ + 6 * PLANE + 221184);

    k_prep<<<576, 256, 0, stream>>>(Wq, Wkv, Wo, WT, WoT);
    k_lnqkv<<<Mtot / 64, 256, 0, stream>>>(x, gamma, beta, WT, bq, bkv, QK, V8);
    k_attn<<<4096 * NHd, 256, 0, stream>>>(QK, V8, bkv, AO);
    k_out<<<Mtot / 64, 256, 0, stream>>>(AO, WoT, bo, x, out);
}

// Round 14
// 504.185 us; speedup vs baseline: 1.1190x; 1.0195x over previous
//
#include <hip/hip_runtime.h>
#include <hip/hip_bf16.h>

typedef __bf16 bf16;
typedef __bf16 bf16x8 __attribute__((ext_vector_type(8)));
typedef float f32x4 __attribute__((ext_vector_type(4)));
typedef unsigned int u32x2 __attribute__((ext_vector_type(2)));
typedef unsigned int u32x4 __attribute__((ext_vector_type(4)));

#define DEVI static __device__ __forceinline__

static constexpr int Bn = 4, Cc = 192, Hh = 256, Wd = 256;
static constexpr int NHd = 6, HD = 32;
static constexpr int Mtot = Bn * Hh * Wd;          // 262144 pixels
static constexpr float EPSv = 1e-5f;
static constexpr float SCQ = 0.2550629072427404f;  // hd^-0.5 * log2(e), folded into Q

DEVI f32x4 mfma16(bf16x8 a, bf16x8 b, f32x4 c) {
    return __builtin_amdgcn_mfma_f32_16x16x32_bf16(a, b, c, 0, 0, 0);
}

DEVI f32x4 mfma16f8(long long a, long long b, f32x4 c) {
    return __builtin_amdgcn_mfma_f32_16x16x32_fp8_fp8(a, b, c, 0, 0, 0);
}

DEVI unsigned cvtpk_bf16(float lo, float hi) {
    unsigned r;
    asm("v_cvt_pk_bf16_f32 %0, %1, %2" : "=v"(r) : "v"(lo), "v"(hi));
    return r;
}

template <bool HIGH>
DEVI unsigned cvtpk_fp8(float lo, float hi, unsigned old) {
    return (unsigned)__builtin_amdgcn_cvt_pk_fp8_f32(lo, hi, (int)old, HIGH);
}

// ---------------------------------------------------------------- K0: weights
// WT576[n][k]: rows 0..191 = Wq^T * SCQ, rows 192..575 = Wkv^T.  WoT = Wo^T.
__global__ __launch_bounds__(256) void k_prep(const float* Wq, const float* Wkv,
                                              const float* Wo, bf16* WT, bf16* WoT) {
    int idx = blockIdx.x * 256 + threadIdx.x;
    if (idx < 576 * 192) {
        int n = idx / 192, k = idx % 192;
        float v = (n < 192) ? Wq[k * 192 + n] * SCQ : Wkv[k * 384 + (n - 192)];
        WT[idx] = (bf16)v;
    } else if (idx < 576 * 192 + 192 * 192) {
        int j = idx - 576 * 192;
        int n = j / 192, k = j % 192;
        WoT[j] = (bf16)Wo[k * 192 + n];
    }
}

// ---------------------------------------------------------------- K1: fused LN + QKV projection
// r8 structure (nt-outer, W read once). Q(pre-scaled),K -> bf16 planes; V -> fp8.
__global__ __launch_bounds__(256) void k_lnqkv(const float* __restrict__ x,
                                               const float* __restrict__ gamma,
                                               const float* __restrict__ beta,
                                               const bf16* __restrict__ WT,
                                               const float* __restrict__ bq,
                                               const float* __restrict__ bkv,
                                               bf16* __restrict__ QK,
                                               unsigned char* __restrict__ V8) {
    constexpr int AS = 200;                       // A-tile stride
    __shared__ __align__(16) bf16 A[64 * AS];
    __shared__ float red[2][4][64];
    __shared__ float sg[Cc], sbv[Cc];

    int tid = threadIdx.x;
    int q = tid >> 6, p = tid & 63;
    int base = blockIdx.x * 64;
    int b = base >> 16;
    int hw = base & 65535;
    int h = hw >> 8, w0 = hw & 255;
    if (tid < Cc) { sg[tid] = gamma[tid]; sbv[tid] = beta[tid]; }

    // pass 1: 48 channels per wave; stats in f32, stash bf16 copy in A
    const float* xb = x + ((size_t)(b * Cc + q * 48) * Hh + h) * Wd + w0 + p;
    float s = 0.f, s2 = 0.f;
#pragma unroll
    for (int i0 = 0; i0 < 48; i0 += 8) {
        bf16x8 o;
#pragma unroll
        for (int j = 0; j < 8; ++j) {
            float v = xb[(size_t)(i0 + j) * Hh * Wd];
            s += v; s2 += v * v; o[j] = (bf16)v;
        }
        *(bf16x8*)&A[p * AS + q * 48 + i0] = o;
    }
    red[0][q][p] = s; red[1][q][p] = s2;
    __syncthreads();
    float mu = (red[0][0][p] + red[0][1][p] + red[0][2][p] + red[0][3][p]) * (1.f / 192.f);
    float m2 = (red[1][0][p] + red[1][1][p] + red[1][2][p] + red[1][3][p]) * (1.f / 192.f);
    float rs = rsqrtf(m2 - mu * mu + EPSv);
    // pass 2: normalize in place
#pragma unroll
    for (int i0 = 0; i0 < 48; i0 += 8) {
        bf16x8 v8 = *(bf16x8*)&A[p * AS + q * 48 + i0];
        bf16x8 o;
#pragma unroll
        for (int j = 0; j < 8; ++j) {
            int c = q * 48 + i0 + j;
            o[j] = (bf16)(((float)v8[j] - mu) * rs * sg[c] + sbv[c]);
        }
        *(bf16x8*)&A[p * AS + q * 48 + i0] = o;
    }
    __syncthreads();

    // GEMM: 4 waves x 144 cols; nt streamed OUTER (W read once), mt inner.
    int lane = tid & 63, l15 = lane & 15, g = lane >> 4;
    const bf16* Wbase = WT + (size_t)(q * 144 + l15) * Cc + g * 8;
#pragma unroll 1
    for (int nt = 0; nt < 9; ++nt) {
        f32x4 acc[4] = {};
        const bf16* wp = Wbase + (size_t)nt * 16 * Cc;
#pragma unroll
        for (int kk = 0; kk < 6; ++kk) {
            bf16x8 wb = *(const bf16x8*)(wp + kk * 32);
#pragma unroll
            for (int mt = 0; mt < 4; ++mt) {
                bf16x8 a = *(bf16x8*)&A[(mt * 16 + l15) * AS + kk * 32 + g * 8];
                acc[mt] = mfma16(wb, a, acc[mt]);   // D[n][pix]
            }
        }
        int n0 = q * 144 + nt * 16 + g * 4;         // 4-group never crosses plane
        const float* bsrc = (n0 < 192) ? (bq + n0) : (bkv + n0 - 192);
        f32x4 b4 = *(const f32x4*)bsrc;
        if (n0 < 192) b4 *= SCQ;                    // Q bias pre-scaled like Wq
        if (n0 < 384) {                              // Q or K bf16 plane
            bf16* outp = QK + (size_t)(n0 >> 5) * Mtot * HD + (n0 & 31);
#pragma unroll
            for (int mt = 0; mt < 4; ++mt) {
                u32x2 pk;
                pk[0] = cvtpk_bf16(acc[mt][0] + b4[0], acc[mt][1] + b4[1]);
                pk[1] = cvtpk_bf16(acc[mt][2] + b4[2], acc[mt][3] + b4[3]);
                *(u32x2*)(outp + (size_t)(base + mt * 16 + l15) * HD) = pk;
            }
        } else {                                     // V fp8 plane [pix][32]
            int vh = (n0 - 384) >> 5;
            unsigned char* outp = V8 + (size_t)vh * Mtot * HD + ((n0 - 384) & 31);
#pragma unroll
            for (int mt = 0; mt < 4; ++mt) {
                unsigned pk = 0;
                pk = cvtpk_fp8<false>(acc[mt][0] + b4[0], acc[mt][1] + b4[1], pk);
                pk = cvtpk_fp8<true>(acc[mt][2] + b4[2], acc[mt][3] + b4[3], pk);
                *(unsigned*)(outp + (size_t)(base + mt * 16 + l15) * HD) = pk;
            }
        }
    }
}

// ---------------------------------------------------------------- K2: attention
// fp8 PV, in-register P via shuffles, LDS = V^T only (8.4KB).
// QK^T+exp chunked (2x8 tiles) to shrink live registers; Q pre-scaled so
// exp2 takes raw s; setprio around MFMA clusters.
__global__ __launch_bounds__(256) void k_attn(const bf16* __restrict__ QK,
                                              const unsigned char* __restrict__ V8,
                                              const float* __restrict__ bkv,
                                              bf16* __restrict__ O) {
    constexpr int VS = 264;                        // VT row stride BYTES
    int bid = blockIdx.x;
    bid = (bid & 7) * 3072 + (bid >> 3);          // chunked XCD swizzle (24576 = 8*3072)
    int head = bid >> 12;                          // /4096
    int win = bid & 4095;
    int b = win >> 10, wloc = win & 1023;
    int h0 = ((wloc >> 5) << 3), w0 = ((wloc & 31) << 3);
    bool interior = (h0 != 0) && (h0 != Hh - 8) && (w0 != 0) && (w0 != Wd - 8);

    int tid = threadIdx.x, wave = tid >> 6, lane = tid & 63;
    int l15 = lane & 15, g = lane >> 4;

    const bf16* Qh = QK + (size_t)head * Mtot * HD;
    const bf16* Kh = QK + (size_t)(6 + head) * Mtot * HD;
    const unsigned char* Vh = V8 + (size_t)head * Mtot * HD;
    bf16* Oh = O + (size_t)head * Mtot * HD;
    long long p00 = (long long)(b * Hh + h0 - 4) * Wd + (w0 - 4);

    __shared__ __align__(16) unsigned char VT8[32 * VS];  // fp8 V^T [d][kv]

    // ---- stage V^T (one kv row per thread), fp8
    {
        int r = tid;
        unsigned wv[8];
        if (interior) {
            const unsigned char* vr = Vh + (p00 + (r >> 4) * Wd + (r & 15)) * HD;
            u32x4 a0 = *(const u32x4*)(vr);
            u32x4 a1 = *(const u32x4*)(vr + 16);
#pragma unroll
            for (int w = 0; w < 4; ++w) { wv[w] = a0[w]; wv[w + 4] = a1[w]; }
        } else {
            int ph = h0 - 4 + (r >> 4), pw = w0 - 4 + (r & 15);
            bool ok = ((unsigned)ph < (unsigned)Hh) && ((unsigned)pw < (unsigned)Wd);
            long long pix = ok ? ((long long)(b * Hh + ph) * Wd + pw) : 0;
            const unsigned char* vr = Vh + pix * HD;
            u32x4 a0 = *(const u32x4*)(vr);
            u32x4 a1 = *(const u32x4*)(vr + 16);
            const float* vb = bkv + Cc + head * HD;
#pragma unroll
            for (int w = 0; w < 8; ++w) {
                unsigned bw = 0;
                bw = cvtpk_fp8<false>(vb[4 * w], vb[4 * w + 1], bw);
                bw = cvtpk_fp8<true>(vb[4 * w + 2], vb[4 * w + 3], bw);
                unsigned lw = (w < 4) ? a0[w] : a1[w - 4];
                wv[w] = ok ? lw : bw;
            }
        }
#pragma unroll
        for (int w = 0; w < 8; ++w) {
            unsigned word = wv[w];
            VT8[(4 * w + 0) * VS + r] = (unsigned char)(word);
            VT8[(4 * w + 1) * VS + r] = (unsigned char)(word >> 8);
            VT8[(4 * w + 2) * VS + r] = (unsigned char)(word >> 16);
            VT8[(4 * w + 3) * VS + r] = (unsigned char)(word >> 24);
        }
    }

    // ---- Q fragment (B-operand): lane l15 holds Q row wave*16+l15
    int qr = wave * 16 + l15;
    size_t qpix = (size_t)(b * Hh + h0 + (qr >> 3)) * Wd + w0 + (qr & 7);
    bf16x8 aq = *(const bf16x8*)(Qh + qpix * HD + g * 8);
    __syncthreads();

    // ---- S^T = K @ Q^T fused with exp/pack, 2 chunks of 8 kv-tiles
    const f32x4 z = {0.f, 0.f, 0.f, 0.f};
    const bf16* kp = Kh + (p00 + l15) * HD + g * 8;
    float sr0 = 0.f, sr1 = 0.f, sr2 = 0.f, sr3 = 0.f;
    unsigned pk[16];
    bf16x8 kb;
    bool colok = true;
    if (!interior) {
#pragma unroll
        for (int j = 0; j < 8; ++j) kb[j] = (bf16)bkv[head * HD + g * 8 + j];
        colok = ((unsigned)(w0 - 4 + l15) < (unsigned)Wd);
    }
#pragma unroll 1
    for (int c = 0; c < 2; ++c) {
        f32x4 s8[8];
        __builtin_amdgcn_s_setprio(1);
        if (interior) {
#pragma unroll
            for (int u = 0; u < 8; ++u) {
                bf16x8 kf = *(const bf16x8*)(kp + (size_t)(c * 8 + u) * Wd * HD);
                s8[u] = mfma16(kf, aq, z);
            }
        } else {
#pragma unroll
            for (int u = 0; u < 8; ++u) {
                int t = c * 8 + u;
                int ph = h0 - 4 + t;              // wave-uniform
                bf16x8 kf;
                if ((unsigned)ph < (unsigned)Hh) {
                    kf = *(const bf16x8*)(kp + (size_t)t * Wd * HD);
                    kf = colok ? kf : kb;
                } else {
                    kf = kb;
                }
                s8[u] = mfma16(kf, aq, z);
            }
        }
        __builtin_amdgcn_s_setprio(0);
#pragma unroll
        for (int u = 0; u < 8; ++u) {
            float p0 = __builtin_amdgcn_exp2f(s8[u][0]);
            float p1 = __builtin_amdgcn_exp2f(s8[u][1]);
            float p2 = __builtin_amdgcn_exp2f(s8[u][2]);
            float p3 = __builtin_amdgcn_exp2f(s8[u][3]);
            sr0 += p0; sr1 += p1; sr2 += p2; sr3 += p3;
            unsigned w = 0;
            w = cvtpk_fp8<false>(p0, p1, w);
            w = cvtpk_fp8<true>(p2, p3, w);
            pk[c * 8 + u] = w;
        }
    }
    float sum = (sr0 + sr1) + (sr2 + sr3);
    sum += __shfl_xor(sum, 16);
    sum += __shfl_xor(sum, 32);
    float inv = __builtin_amdgcn_rcpf(sum);

    // ---- O = P @ V in fp8; A-fragments gathered by lane shuffle
    f32x4 o[2] = {};
    int srcA = l15 | ((2 * (g & 1)) << 4);
    int srcB = srcA + 16;
    bool ghi = (g >> 1) != 0;
#pragma unroll
    for (int kk = 0; kk < 8; ++kk) {
        unsigned sa = __shfl(pk[2 * kk], srcA);
        unsigned sb = __shfl(pk[2 * kk + 1], srcA);
        unsigned scc = __shfl(pk[2 * kk], srcB);
        unsigned sd = __shfl(pk[2 * kk + 1], srcB);
        unsigned lo = ghi ? sb : sa;
        unsigned hi = ghi ? sd : scc;
        long long ap = (long long)(((unsigned long long)hi << 32) | lo);
        __builtin_amdgcn_s_setprio(1);
#pragma unroll
        for (int nt = 0; nt < 2; ++nt) {
            long long bv = *(const long long*)&VT8[(nt * 16 + l15) * VS + kk * 32 + g * 8];
            o[nt] = mfma16f8(ap, bv, o[nt]);
        }
        __builtin_amdgcn_s_setprio(0);
    }
    // inv for epilogue rows g*4+r lives in lanes with l15 == g*4+r (same g ok)
    float invr[4];
#pragma unroll
    for (int r = 0; r < 4; ++r)
        invr[r] = __shfl(inv, (lane & 48) | (g * 4 + r));
#pragma unroll
    for (int nt = 0; nt < 2; ++nt)
#pragma unroll
        for (int r = 0; r < 4; ++r) {
            int row = wave * 16 + g * 4 + r;
            size_t pix = (size_t)(b * Hh + h0 + (row >> 3)) * Wd + w0 + (row & 7);
            Oh[pix * HD + nt * 16 + l15] = (bf16)(o[nt][r] * invr[r]);
        }
}

// ---------------------------------------------------------------- K3: O-proj + residual (BHWC->BCHW)
__global__ __launch_bounds__(256) void k_out(const bf16* __restrict__ AO,
                                             const bf16* __restrict__ WoT,
                                             const float* __restrict__ bo,
                                             const float* __restrict__ x,
                                             float* __restrict__ out) {
    int row0 = blockIdx.x * 64;
    int tid = threadIdx.x, wave = tid >> 6, lane = tid & 63;
    int l15 = lane & 15, g = lane >> 4;
    int nb = wave * 48;
    f32x4 acc[4][3] = {};
    const bf16* Arow[4];
#pragma unroll
    for (int mt = 0; mt < 4; ++mt) Arow[mt] = AO + (size_t)(row0 + mt * 16 + l15) * HD + g * 8;
    const bf16* Wrow[3];
#pragma unroll
    for (int nt = 0; nt < 3; ++nt) Wrow[nt] = WoT + (size_t)(nb + nt * 16 + l15) * Cc + g * 8;
#pragma unroll
    for (int kk = 0; kk < 6; ++kk) {
        bf16x8 a[4];
#pragma unroll
        for (int mt = 0; mt < 4; ++mt)
            a[mt] = *(const bf16x8*)(Arow[mt] + (size_t)kk * Mtot * HD);
#pragma unroll
        for (int nt = 0; nt < 3; ++nt) {
            bf16x8 bb = *(const bf16x8*)(Wrow[nt] + kk * 32);
#pragma unroll
            for (int mt = 0; mt < 4; ++mt) acc[mt][nt] = mfma16(a[mt], bb, acc[mt][nt]);
        }
    }
    __shared__ float st[192 * 65];
#pragma unroll
    for (int nt = 0; nt < 3; ++nt) {
        float bval = bo[nb + nt * 16 + l15];
#pragma unroll
        for (int mt = 0; mt < 4; ++mt)
#pragma unroll
            for (int r = 0; r < 4; ++r) {
                int ccol = nb + nt * 16 + l15;
                int px = mt * 16 + g * 4 + r;
                st[ccol * 65 + px] = acc[mt][nt][r] + bval;
            }
    }
    __syncthreads();
    int bb2 = row0 / (Hh * Wd);
    int rem = row0 % (Hh * Wd);
    int h = rem / Wd, wstart = rem % Wd;
    for (int idx = tid; idx < 192 * 64; idx += 256) {
        int cc = idx >> 6, px = idx & 63;
        size_t ga = ((size_t)(bb2 * Cc + cc) * Hh + h) * Wd + wstart + px;
        out[ga] = st[cc * 65 + px] + x[ga];
    }
}

// ---------------------------------------------------------------- launch
extern "C" void kernel_launch(void* const* d_in, const int* in_sizes, int n_in,
                              void* d_out, int out_size, void* d_ws, size_t ws_size,
                              hipStream_t stream) {
    const float* x     = (const float*)d_in[0];
    const float* gamma = (const float*)d_in[1];
    const float* beta  = (const float*)d_in[2];
    const float* Wq    = (const float*)d_in[3];
    const float* bq    = (const float*)d_in[4];
    const float* Wkv   = (const float*)d_in[5];
    const float* bkv   = (const float*)d_in[6];
    const float* Wo    = (const float*)d_in[7];
    const float* bo    = (const float*)d_in[8];
    float* out = (float*)d_out;

    char* ws = (char*)d_ws;
    constexpr size_t PLANE = (size_t)Mtot * HD * 2;        // 16777216 B (bf16 plane)
    constexpr size_t QKSZ  = 12 * PLANE;                    // Q(6) + K(6)
    constexpr size_t V8SZ  = (size_t)NHd * Mtot * HD;       // 50331648 B (fp8)
    bf16*          QK  = (bf16*)(ws);
    unsigned char* V8  = (unsigned char*)(ws + QKSZ);
    bf16*          AO  = (bf16*)(ws + QKSZ + V8SZ);         // 6 bf16 planes
    bf16*          WT  = (bf16*)(ws + QKSZ + V8SZ + 6 * PLANE);
    bf16*          WoT = (bf16*)(ws + QKSZ + V8SZ + 6 * PLANE + 221184);

    k_prep<<<576, 256, 0, stream>>>(Wq, Wkv, Wo, WT, WoT);
    k_lnqkv<<<Mtot / 64, 256, 0, stream>>>(x, gamma, beta, WT, bq, bkv, QK, V8);
    k_attn<<<4096 * NHd, 256, 0, stream>>>(QK, V8, bkv, AO);
    k_out<<<Mtot / 64, 256, 0, stream>>>(AO, WoT, bo, x, out);
}